// Round 21
// baseline (163.900 us; speedup 1.0000x reference)
//
#include <hip/hip_runtime.h>
#include <hip/hip_bf16.h>

typedef __attribute__((ext_vector_type(4))) float f32x4;
typedef __attribute__((ext_vector_type(16))) float f32x16;
typedef __attribute__((ext_vector_type(8))) short bf8;
typedef __attribute__((ext_vector_type(2))) int i32x2;

#define B_ 2
#define ST 2048
#define SC 1024
#define SK 3072
#define NH 16
#define DH 128
#define KVB 32
#define NT 96
#define TGT 64
#define SCALE 0.088388347648318447f
#define LOG2E 1.4426950408889634f
// pre-converted KV workspace: 32 bh x 96 tiles x 512 chunks x 16 B, K then V
// chunk = exact 16B MFMA fragment for lane l (lane-linear, conflict-free)
#define PRE_TILE_U32 2048
#define PRE_BYTES (32ull * 96 * 512 * 16)
#define WS_NEED (2ull * PRE_BYTES)

__device__ __forceinline__ i32x2 tr_read(unsigned a) {
    i32x2 d;
    asm volatile("ds_read_b64_tr_b16 %0, %1" : "=v"(d) : "v"(a));
    return d;
}

__device__ __forceinline__ unsigned cvtpk(float lo, float hi) {
    unsigned r;
    asm("v_cvt_pk_bf16_f32 %0, %1, %2" : "=v"(r) : "v"(lo), "v"(hi));
    return r;
}

// v_permlane32_swap_b32: SAFE only with two independently-computed values
// (P-pack, proven R7). BROKEN as copy-then-swap self-reduce (R6/R8).
__device__ __forceinline__ void swap32(unsigned &a, unsigned &b) {
    asm volatile("v_permlane32_swap_b32 %0, %1" : "+v"(a), "+v"(b));
}

__device__ __forceinline__ bf8 mk_bf8(i32x2 a, i32x2 b) {
    union { i32x2 h[2]; bf8 v; } u;
    u.h[0] = a; u.h[1] = b;
    return u.v;
}
__device__ __forceinline__ bf8 mk_bf8w(unsigned w0, unsigned w1, unsigned w2, unsigned w3) {
    union { unsigned w[4]; bf8 v; } u;
    u.w[0] = w0; u.w[1] = w1; u.w[2] = w2; u.w[3] = w3;
    return u.v;
}
__device__ __forceinline__ bf8 pack_bf8(f32x4 a, f32x4 b) {
    return mk_bf8w(cvtpk(a[0], a[1]), cvtpk(a[2], a[3]),
                   cvtpk(b[0], b[1]), cvtpk(b[2], b[3]));
}

// ---------------- pre-pass: fp32 KV -> bf16 fragments in lane-linear order ----
__global__ __launch_bounds__(256)
void preconv(const float* __restrict__ TK, const float* __restrict__ TV,
             const float* __restrict__ CK, const float* __restrict__ CV,
             unsigned* __restrict__ KP, unsigned* __restrict__ VP)
{
    const unsigned gid = blockIdx.x * 256 + threadIdx.x;   // 0..1572863
    const int c    = gid & 511;
    const int idx  = gid >> 9;          // bh*96 + t
    const int bhid = idx / 96;
    const int t    = idx - bhid * 96;
    const int bb   = bhid >> 4;
    const int hh   = bhid & 15;
    const int lc   = c & 63;
    const int r31c = lc & 31;
    const int hic  = lc >> 5;

    const bool tgt = (t < TGT);
    const size_t krowbase = tgt
        ? (((size_t)bb * ST + t * 32) * NH + hh) * DH
        : (((size_t)bb * SC + (t * 32 - ST)) * NH + hh) * DH;
    const float* kb = (tgt ? TK : CK) + krowbase;
    const float* vb = (tgt ? TV : CV) + krowbase;

    // K chunk: dk = c>>6; lane fragment = K[kv=r31][dk*16 + hi*8 + j], j=0..7
    {
        const int dk = c >> 6;
        const float* kp = kb + (size_t)r31c * (NH * DH) + dk * 16 + hic * 8;
        const f32x4 k0 = *(const f32x4*)kp;
        const f32x4 k1 = *(const f32x4*)(kp + 4);
        unsigned* ko = KP + (size_t)gid * 4;
        ko[0] = cvtpk(k0[0], k0[1]); ko[1] = cvtpk(k0[2], k0[3]);
        ko[2] = cvtpk(k1[0], k1[1]); ko[3] = cvtpk(k1[2], k1[3]);
    }

    // V chunk: s = c>>6 = ks*4+dt; lane fragment = V^T[d=dt*32+(lc&31)]
    //          [kv = ks*16 + hi*8 + j] = V[kv+j][d]
    {
        const int s  = c >> 6;
        const int ks = s >> 2;
        const int dt = s & 3;
        const int d  = dt * 32 + r31c;
        const float* vp = vb + (size_t)(ks * 16 + hic * 8) * (NH * DH) + d;
        float vv[8];
#pragma unroll
        for (int j = 0; j < 8; ++j) vv[j] = vp[(size_t)j * (NH * DH)];
        unsigned* vo = VP + (size_t)gid * 4;
        vo[0] = cvtpk(vv[0], vv[1]); vo[1] = cvtpk(vv[2], vv[3]);
        vo[2] = cvtpk(vv[4], vv[5]); vo[3] = cvtpk(vv[6], vv[7]);
    }
}

// ---------------- main: registers-only, barrier-free, zero LDS ---------------
__global__ __launch_bounds__(256) __attribute__((amdgpu_waves_per_eu(2, 2)))
void attn_fwd_pre(const float* __restrict__ Q,
                  const unsigned* __restrict__ KP,
                  const unsigned* __restrict__ VP,
                  const float* __restrict__ BP,
                  float* __restrict__ OUT)
{
    // Fragments load straight from the pre-permuted buffer into VGPRs:
    // K double-buffered one tile ahead; V issued at body top, consumed after
    // QK+softmax (~450 cyc runway covers L2-hit latency). No LDS, no barriers.
    const int tid = threadIdx.x;
    const int w   = tid >> 6;
    const int l   = tid & 63;
    const int r31 = l & 31;
    const int hi  = l >> 5;

    // XCD-aware mapping: 512 blocks = 8 XCD x 4 bh x 16 q-tiles
    const int bid = blockIdx.x;
    const int xcd = bid & 7;
    const int sub = bid >> 3;
    const int bh  = xcd * 4 + (sub >> 4);
    const int qt  = sub & 15;
    const int bb  = bh >> 4;
    const int hh  = bh & 15;
    const int bh96 = bh * 96;

    const float biasl = BP[0] * LOG2E;

    // ---- Q fragments (B-operand), pre-scaled by SCALE*log2(e) ----
    const int qrow = qt * 128 + w * 32 + r31;
    const float* qp = Q + (((size_t)bb * ST + qrow) * NH + hh) * DH;
    const float qsc = SCALE * LOG2E;
    bf8 qf[8];
#pragma unroll
    for (int dk = 0; dk < 8; ++dk) {
        const f32x4 x0 = *(const f32x4*)(qp + dk * 16 + hi * 8);
        const f32x4 x1 = *(const f32x4*)(qp + dk * 16 + hi * 8 + 4);
        qf[dk] = mk_bf8w(cvtpk(x0[0]*qsc, x0[1]*qsc), cvtpk(x0[2]*qsc, x0[3]*qsc),
                         cvtpk(x1[0]*qsc, x1[1]*qsc), cvtpk(x1[2]*qsc, x1[3]*qsc));
    }

    f32x16 oa[4];
#pragma unroll
    for (int dt = 0; dt < 4; ++dt)
#pragma unroll
        for (int e = 0; e < 16; ++e) oa[dt][e] = 0.f;
    float l_run = 0.f;

    const char* kBase = (const char*)KP + (size_t)bh96 * 8192 + (size_t)l * 16;
    const char* vBase = (const char*)VP + (size_t)bh96 * 8192 + (size_t)l * 16;

    bf8 kA[8], kB[8], vC[8];

    // prologue: K(0) into kA
    {
        const char* kt = kBase;
#pragma unroll
        for (int i = 0; i < 8; ++i)
            kA[i] = *(const bf8*)(kt + i * 1024);
    }

    auto body = [&](int t, bf8* kCur, bf8* kNext) {
        // issue V(t) loads (consumed after QK+softmax)
        const char* vt = vBase + (size_t)t * 8192;
#pragma unroll
        for (int i = 0; i < 8; ++i)
            vC[i] = *(const bf8*)(vt + i * 1024);
        // issue K(t+1) loads (consumed at next body's QK: full body runway)
        if (t + 1 < NT) {
            const char* kt = kBase + (size_t)(t + 1) * 8192;
#pragma unroll
            for (int i = 0; i < 8; ++i)
                kNext[i] = *(const bf8*)(kt + i * 1024);
        }

        // ---- QK^T swapped: single accumulator chain, bias in C-init ----
        const float bias = (t >= TGT) ? biasl : 0.f;
        f32x16 s;
#pragma unroll
        for (int e = 0; e < 16; ++e) s[e] = bias;
        __builtin_amdgcn_s_setprio(1);
#pragma unroll
        for (int dk = 0; dk < 8; ++dk)
            s = __builtin_amdgcn_mfma_f32_32x32x16_bf16(kCur[dk], qf[dk], s, 0, 0, 0);
        __builtin_amdgcn_s_setprio(0);

        // ---- static softmax: p = exp2(s), no max, no cross-lane ----
        float rs = 0.f;
#pragma unroll
        for (int e = 0; e < 16; ++e) {
            s[e] = __builtin_amdgcn_exp2f(s[e]);
            rs += s[e];
        }
        l_run += rs;

        // ---- pack P -> B-operand fragments (cvt_pk + permlane) ----
        unsigned a0 = cvtpk(s[0], s[1]),  c0 = cvtpk(s[4], s[5]);
        unsigned a1 = cvtpk(s[2], s[3]),  c1 = cvtpk(s[6], s[7]);
        swap32(a0, c0); swap32(a1, c1);
        const bf8 pf0 = mk_bf8w(a0, a1, c0, c1);
        unsigned a2 = cvtpk(s[8], s[9]),   c2 = cvtpk(s[12], s[13]);
        unsigned a3 = cvtpk(s[10], s[11]), c3 = cvtpk(s[14], s[15]);
        swap32(a2, c2); swap32(a3, c3);
        const bf8 pf1 = mk_bf8w(a2, a3, c2, c3);

        // ---- PV: two 4-MFMA clusters (A = V^T fragments) ----
        __builtin_amdgcn_s_setprio(1);
#pragma unroll
        for (int dt = 0; dt < 4; ++dt)
            oa[dt] = __builtin_amdgcn_mfma_f32_32x32x16_bf16(vC[dt], pf0, oa[dt], 0, 0, 0);
#pragma unroll
        for (int dt = 0; dt < 4; ++dt)
            oa[dt] = __builtin_amdgcn_mfma_f32_32x32x16_bf16(vC[4 + dt], pf1, oa[dt], 0, 0, 0);
        __builtin_amdgcn_s_setprio(0);
    };

    for (int t = 0; t < NT; t += 2) {
        body(t, kA, kB);
        body(t + 1, kB, kA);
    }

    // ---- epilogue: single cross-half l merge, normalize, store ----
    const float l_tot = l_run + __shfl_xor(l_run, 32);
    const float inv = 1.0f / l_tot;
    float* op = OUT + ((size_t)(bb * ST + qrow)) * (NH * DH) + hh * DH;
#pragma unroll
    for (int dt = 0; dt < 4; ++dt)
#pragma unroll
        for (int rr = 0; rr < 4; ++rr) {
            f32x4 st;
            st[0] = oa[dt][rr * 4 + 0] * inv;
            st[1] = oa[dt][rr * 4 + 1] * inv;
            st[2] = oa[dt][rr * 4 + 2] * inv;
            st[3] = oa[dt][rr * 4 + 3] * inv;
            *(f32x4*)(op + dt * 32 + rr * 8 + hi * 4) = st;
        }
}

// ---------------- fallback: R16 self-staging kernel (ws too small) ----------
__global__ __launch_bounds__(256, 2)
void attn_fwd_reg(const float* __restrict__ Q,
                  const float* __restrict__ TK,
                  const float* __restrict__ TV,
                  const float* __restrict__ CK,
                  const float* __restrict__ CV,
                  const float* __restrict__ BP,
                  float* __restrict__ OUT)
{
    __shared__ __align__(16) unsigned short Ks[2][KVB * DH];
    __shared__ __align__(16) unsigned short Vs[2][KVB * DH];

    const int tid = threadIdx.x;
    const int w   = tid >> 6;
    const int l   = tid & 63;
    const int r31 = l & 31;
    const int hi  = l >> 5;

    const int bid = blockIdx.x;
    const int xcd = bid & 7;
    const int sub = bid >> 3;
    const int bh  = xcd * 4 + (sub >> 4);
    const int qt  = sub & 15;
    const int bb  = bh >> 4;
    const int hh  = bh & 15;

    const float biasl = BP[0] * LOG2E;

    const int qrow = qt * 128 + w * 32 + r31;
    const float* qp = Q + (((size_t)bb * ST + qrow) * NH + hh) * DH;
    const float qsc = SCALE * LOG2E;
    bf8 qf[8];
#pragma unroll
    for (int dk = 0; dk < 8; ++dk) {
        const f32x4 x0 = *(const f32x4*)(qp + dk * 16 + hi * 8);
        const f32x4 x1 = *(const f32x4*)(qp + dk * 16 + hi * 8 + 4);
        qf[dk] = mk_bf8w(cvtpk(x0[0]*qsc, x0[1]*qsc), cvtpk(x0[2]*qsc, x0[3]*qsc),
                         cvtpk(x1[0]*qsc, x1[1]*qsc), cvtpk(x1[2]*qsc, x1[3]*qsc));
    }

    f32x16 oa[4];
#pragma unroll
    for (int dt = 0; dt < 4; ++dt)
#pragma unroll
        for (int e = 0; e < 16; ++e) oa[dt][e] = 0.f;
    float l_run = 0.f;

    f32x4 skr[2][2], svr[2][2];

    auto stage_load = [&](int t) {
        const int kv0 = t * KVB;
        const float *kb, *vb;
        if (kv0 < ST) {
            const size_t off = (((size_t)bb * ST + kv0) * NH + hh) * DH;
            kb = TK + off; vb = TV + off;
        } else {
            const size_t off = (((size_t)bb * SC + (kv0 - ST)) * NH + hh) * DH;
            kb = CK + off; vb = CV + off;
        }
#pragma unroll
        for (int i = 0; i < 2; ++i) {
            const int c = tid + (i << 8);
            const int krow = c >> 4;
            const int kcol = ((c & 15) ^ (krow & 7)) << 3;
            const float* kp = kb + (size_t)krow * (NH * DH) + kcol;
            skr[i][0] = *(const f32x4*)kp;
            skr[i][1] = *(const f32x4*)(kp + 4);
            const int vkv = (((c >> 8) & 1) << 4) | (((c >> 4) & 1) << 3)
                          | (((c >> 7) & 1) << 2) | ((c >> 1) & 3);
            const int vd  = (((c >> 5) & 3) << 5) | (((c >> 3) & 1) << 4)
                          | ((c & 1) << 3);
            const float* vp = vb + (size_t)vkv * (NH * DH) + vd;
            svr[i][0] = *(const f32x4*)vp;
            svr[i][1] = *(const f32x4*)(vp + 4);
        }
    };
    auto stage_write = [&](int buf) {
#pragma unroll
        for (int i = 0; i < 2; ++i) {
            const int c = tid + (i << 8);
            *(bf8*)((char*)Ks[buf] + c * 16) = pack_bf8(skr[i][0], skr[i][1]);
            *(bf8*)((char*)Vs[buf] + c * 16) = pack_bf8(svr[i][0], svr[i][1]);
        }
    };

    stage_load(0);
    stage_write(0);

    const unsigned vLane = (unsigned)(size_t)&Vs[0][0]
                         + (unsigned)((l >> 4) * 128 + (l & 15) * 8);

    for (int t = 0; t < NT; ++t) {
        __syncthreads();
        if (t + 1 < NT) stage_load(t + 1);
        const int buf = t & 1;
        const float bias = (t >= TGT) ? biasl : 0.f;

        f32x16 s0;
#pragma unroll
        for (int e = 0; e < 16; ++e) s0[e] = bias;
        __builtin_amdgcn_s_setprio(1);
#pragma unroll
        for (int dk = 0; dk < 8; ++dk) {
            int o = r31 * 256 + (dk * 16 + hi * 8) * 2;
            o ^= (r31 & 7) << 4;
            const bf8 kf = *(const bf8*)((const char*)Ks[buf] + o);
            s0 = __builtin_amdgcn_mfma_f32_32x32x16_bf16(kf, qf[dk], s0, 0, 0, 0);
        }
        __builtin_amdgcn_s_setprio(0);

        asm volatile("" ::: "memory");
        const unsigned vA = vLane + (unsigned)(buf << 13);
        i32x2 vt_[2][4][2];
#pragma unroll
        for (int ks = 0; ks < 2; ++ks) {
            const unsigned vk = vA + (unsigned)(ks << 12);
#pragma unroll
            for (int dt = 0; dt < 4; ++dt) {
                vt_[ks][dt][0] = tr_read(vk + dt * 512);
                vt_[ks][dt][1] = tr_read(vk + dt * 512 + 2048);
            }
        }

        if (t + 1 < NT) stage_write(buf ^ 1);

        float rs = 0.f;
#pragma unroll
        for (int e = 0; e < 16; ++e) {
            s0[e] = __builtin_amdgcn_exp2f(s0[e]);
            rs += s0[e];
        }
        l_run += rs;

        unsigned a0 = cvtpk(s0[0], s0[1]),  b0 = cvtpk(s0[4], s0[5]);
        unsigned a1 = cvtpk(s0[2], s0[3]),  b1 = cvtpk(s0[6], s0[7]);
        swap32(a0, b0); swap32(a1, b1);
        const bf8 pf0 = mk_bf8w(a0, a1, b0, b1);
        unsigned a2 = cvtpk(s0[8], s0[9]),   b2 = cvtpk(s0[12], s0[13]);
        unsigned a3 = cvtpk(s0[10], s0[11]), b3 = cvtpk(s0[14], s0[15]);
        swap32(a2, b2); swap32(a3, b3);
        const bf8 pf1 = mk_bf8w(a2, a3, b2, b3);

        asm volatile("s_waitcnt lgkmcnt(0)");
        __builtin_amdgcn_sched_barrier(0);
        __builtin_amdgcn_s_setprio(1);
#pragma unroll
        for (int ks = 0; ks < 2; ++ks) {
            const bf8 pf = ks ? pf1 : pf0;
#pragma unroll
            for (int dt = 0; dt < 4; ++dt) {
                const bf8 vf = mk_bf8(vt_[ks][dt][0], vt_[ks][dt][1]);
                oa[dt] = __builtin_amdgcn_mfma_f32_32x32x16_bf16(vf, pf, oa[dt], 0, 0, 0);
            }
        }
        __builtin_amdgcn_s_setprio(0);
    }

    const float l_tot = l_run + __shfl_xor(l_run, 32);
    const float inv = 1.0f / l_tot;
    float* op = OUT + ((size_t)(bb * ST + qrow)) * (NH * DH) + hh * DH;
#pragma unroll
    for (int dt = 0; dt < 4; ++dt)
#pragma unroll
        for (int rr = 0; rr < 4; ++rr) {
            f32x4 st;
            st[0] = oa[dt][rr * 4 + 0] * inv;
            st[1] = oa[dt][rr * 4 + 1] * inv;
            st[2] = oa[dt][rr * 4 + 2] * inv;
            st[3] = oa[dt][rr * 4 + 3] * inv;
            *(f32x4*)(op + dt * 32 + rr * 8 + hi * 4) = st;
        }
}

extern "C" void kernel_launch(void* const* d_in, const int* in_sizes, int n_in,
                              void* d_out, int out_size, void* d_ws, size_t ws_size,
                              hipStream_t stream) {
    const float* q  = (const float*)d_in[0];
    const float* tk = (const float*)d_in[1];
    const float* tv = (const float*)d_in[2];
    const float* ck = (const float*)d_in[3];
    const float* cv = (const float*)d_in[4];
    const float* bp = (const float*)d_in[5];
    float* out = (float*)d_out;

    if (ws_size >= WS_NEED) {
        unsigned* kp = (unsigned*)d_ws;
        unsigned* vp = (unsigned*)((char*)d_ws + PRE_BYTES);
        preconv<<<dim3(6144), 256, 0, stream>>>(tk, tv, ck, cv, kp, vp);
        attn_fwd_pre<<<dim3(512), 256, 0, stream>>>(q, kp, vp, bp, out);
    } else {
        attn_fwd_reg<<<dim3(512), 256, 0, stream>>>(q, tk, tv, ck, cv, bp, out);
    }
}

// Round 23
// 141.993 us; speedup vs baseline: 1.1543x; 1.1543x over previous
//
#include <hip/hip_runtime.h>
#include <hip/hip_bf16.h>

typedef __attribute__((ext_vector_type(4))) float f32x4;
typedef __attribute__((ext_vector_type(16))) float f32x16;
typedef __attribute__((ext_vector_type(8))) short bf8;
typedef __attribute__((ext_vector_type(2))) int i32x2;

#define B_ 2
#define ST 2048
#define SC 1024
#define SK 3072
#define NH 16
#define DH 128
#define KVB 32
#define NT 96
#define TGT 64
#define SCALE 0.088388347648318447f
#define LOG2E 1.4426950408889634f
// pre-converted KV workspace: 32 bh x 96 tiles x 512 chunks x 16 B, K then V
// chunk = exact 16B MFMA fragment for lane l (lane-linear, conflict-free)
#define PRE_TILE_U32 2048
#define PRE_BYTES (32ull * 96 * 512 * 16)
#define WS_NEED (2ull * PRE_BYTES)

__device__ __forceinline__ i32x2 tr_read(unsigned a) {
    i32x2 d;
    asm volatile("ds_read_b64_tr_b16 %0, %1" : "=v"(d) : "v"(a));
    return d;
}

__device__ __forceinline__ unsigned cvtpk(float lo, float hi) {
    unsigned r;
    asm("v_cvt_pk_bf16_f32 %0, %1, %2" : "=v"(r) : "v"(lo), "v"(hi));
    return r;
}

// v_permlane32_swap_b32: SAFE only with two independently-computed values
// (P-pack, proven R7). BROKEN as copy-then-swap self-reduce (R6/R8).
__device__ __forceinline__ void swap32(unsigned &a, unsigned &b) {
    asm volatile("v_permlane32_swap_b32 %0, %1" : "+v"(a), "+v"(b));
}

__device__ __forceinline__ bf8 mk_bf8(i32x2 a, i32x2 b) {
    union { i32x2 h[2]; bf8 v; } u;
    u.h[0] = a; u.h[1] = b;
    return u.v;
}
__device__ __forceinline__ bf8 mk_bf8w(unsigned w0, unsigned w1, unsigned w2, unsigned w3) {
    union { unsigned w[4]; bf8 v; } u;
    u.w[0] = w0; u.w[1] = w1; u.w[2] = w2; u.w[3] = w3;
    return u.v;
}
__device__ __forceinline__ bf8 pack_bf8(f32x4 a, f32x4 b) {
    return mk_bf8w(cvtpk(a[0], a[1]), cvtpk(a[2], a[3]),
                   cvtpk(b[0], b[1]), cvtpk(b[2], b[3]));
}

// ---------------- pre-pass: fp32 KV -> bf16 fragments in lane-linear order ----
__global__ __launch_bounds__(256)
void preconv(const float* __restrict__ TK, const float* __restrict__ TV,
             const float* __restrict__ CK, const float* __restrict__ CV,
             unsigned* __restrict__ KP, unsigned* __restrict__ VP)
{
    const unsigned gid = blockIdx.x * 256 + threadIdx.x;   // 0..1572863
    const int c    = gid & 511;
    const int idx  = gid >> 9;          // bh*96 + t
    const int bhid = idx / 96;
    const int t    = idx - bhid * 96;
    const int bb   = bhid >> 4;
    const int hh   = bhid & 15;
    const int lc   = c & 63;
    const int r31c = lc & 31;
    const int hic  = lc >> 5;

    const bool tgt = (t < TGT);
    const size_t krowbase = tgt
        ? (((size_t)bb * ST + t * 32) * NH + hh) * DH
        : (((size_t)bb * SC + (t * 32 - ST)) * NH + hh) * DH;
    const float* kb = (tgt ? TK : CK) + krowbase;
    const float* vb = (tgt ? TV : CV) + krowbase;

    // K chunk: dk = c>>6; lane fragment = K[kv=r31][dk*16 + hi*8 + j], j=0..7
    {
        const int dk = c >> 6;
        const float* kp = kb + (size_t)r31c * (NH * DH) + dk * 16 + hic * 8;
        const f32x4 k0 = *(const f32x4*)kp;
        const f32x4 k1 = *(const f32x4*)(kp + 4);
        unsigned* ko = KP + (size_t)gid * 4;
        ko[0] = cvtpk(k0[0], k0[1]); ko[1] = cvtpk(k0[2], k0[3]);
        ko[2] = cvtpk(k1[0], k1[1]); ko[3] = cvtpk(k1[2], k1[3]);
    }

    // V chunk: s = c>>6 = ks*4+dt; lane fragment = V^T[d=dt*32+(lc&31)]
    //          [kv = ks*16 + hi*8 + j] = V[kv+j][d]
    {
        const int s  = c >> 6;
        const int ks = s >> 2;
        const int dt = s & 3;
        const int d  = dt * 32 + r31c;
        const float* vp = vb + (size_t)(ks * 16 + hic * 8) * (NH * DH) + d;
        float vv[8];
#pragma unroll
        for (int j = 0; j < 8; ++j) vv[j] = vp[(size_t)j * (NH * DH)];
        unsigned* vo = VP + (size_t)gid * 4;
        vo[0] = cvtpk(vv[0], vv[1]); vo[1] = cvtpk(vv[2], vv[3]);
        vo[2] = cvtpk(vv[4], vv[5]); vo[3] = cvtpk(vv[6], vv[7]);
    }
}

// ---- main: lane-linear LDS, 4-buffer counted-vmcnt pipeline, T15 overlap ----
__global__ __launch_bounds__(256) __attribute__((amdgpu_waves_per_eu(2, 2)))
void attn_fwd_pre(const float* __restrict__ Q,
                  const unsigned* __restrict__ KP,
                  const unsigned* __restrict__ VP,
                  const float* __restrict__ BP,
                  float* __restrict__ OUT)
{
    // 4-buffer rotation, stage 2 ahead, stage issued BEFORE the wait.
    // Each stage = 4 global_load_lds per wave; outstanding at wait =
    // tile(t+1):4 + tile(t+2):4 = 8, so s_waitcnt vmcnt(4) drains exactly
    // tile t+1 and leaves tile t+2's 4 in flight across the barrier.
    // (R22's vmcnt(8) drained nothing -> NaN.)
    __shared__ __align__(16) unsigned short Ks[4][KVB * DH];   // 4 x 8 KB
    __shared__ __align__(16) unsigned short Vs[4][KVB * DH];   // 4 x 8 KB

    const int tid = threadIdx.x;
    const int w   = tid >> 6;
    const int l   = tid & 63;
    const int r31 = l & 31;
    const int hi  = l >> 5;

    // XCD-aware mapping: 512 blocks = 8 XCD x 4 bh x 16 q-tiles
    const int bid = blockIdx.x;
    const int xcd = bid & 7;
    const int sub = bid >> 3;
    const int bh  = xcd * 4 + (sub >> 4);
    const int qt  = sub & 15;
    const int bb  = bh >> 4;
    const int hh  = bh & 15;
    const int bh96 = bh * 96;

    const float biasl = BP[0] * LOG2E;

    // ---- Q fragments (B-operand), pre-scaled by SCALE*log2(e) ----
    const int qrow = qt * 128 + w * 32 + r31;
    const float* qp = Q + (((size_t)bb * ST + qrow) * NH + hh) * DH;
    const float qsc = SCALE * LOG2E;
    bf8 qf[8];
#pragma unroll
    for (int dk = 0; dk < 8; ++dk) {
        const f32x4 x0 = *(const f32x4*)(qp + dk * 16 + hi * 8);
        const f32x4 x1 = *(const f32x4*)(qp + dk * 16 + hi * 8 + 4);
        qf[dk] = mk_bf8w(cvtpk(x0[0]*qsc, x0[1]*qsc), cvtpk(x0[2]*qsc, x0[3]*qsc),
                         cvtpk(x1[0]*qsc, x1[1]*qsc), cvtpk(x1[2]*qsc, x1[3]*qsc));
    }

    f32x16 oa[4];
#pragma unroll
    for (int dt = 0; dt < 4; ++dt)
#pragma unroll
        for (int e = 0; e < 16; ++e) oa[dt][e] = 0.f;
    float l_run = 0.f;

    auto stage = [&](int t, int buf) {
        const unsigned* kt = KP + (size_t)(bh96 + t) * PRE_TILE_U32;
        const unsigned* vt = VP + (size_t)(bh96 + t) * PRE_TILE_U32;
#pragma unroll
        for (int i = 0; i < 2; ++i) {
            const int cb = (w << 6) + (i << 8);
            const unsigned kdst = (unsigned)(size_t)&Ks[buf][cb * 8];
            const unsigned vdst = (unsigned)(size_t)&Vs[buf][cb * 8];
            const unsigned* kg = kt + (size_t)(cb + l) * 4;
            const unsigned* vg = vt + (size_t)(cb + l) * 4;
            __builtin_amdgcn_global_load_lds(
                (const __attribute__((address_space(1))) unsigned*)(size_t)kg,
                (__attribute__((address_space(3))) unsigned*)(size_t)kdst, 16, 0, 0);
            __builtin_amdgcn_global_load_lds(
                (const __attribute__((address_space(1))) unsigned*)(size_t)vg,
                (__attribute__((address_space(3))) unsigned*)(size_t)vdst, 16, 0, 0);
        }
    };

    const char* kLane = (const char*)&Ks[0][0] + l * 16;
    const char* vLane = (const char*)&Vs[0][0] + l * 16;

    auto qk_into = [&](f32x16& SN, int bufn, float biasn) {
#pragma unroll
        for (int e = 0; e < 16; ++e) SN[e] = biasn;
        const char* kB = kLane + (unsigned)bufn * 8192u;
        __builtin_amdgcn_s_setprio(1);
#pragma unroll
        for (int dk = 0; dk < 8; ++dk) {
            const bf8 kf = *(const bf8*)(kB + dk * 1024);
            SN = __builtin_amdgcn_mfma_f32_32x32x16_bf16(kf, qf[dk], SN, 0, 0, 0);
        }
        __builtin_amdgcn_s_setprio(0);
    };

    // ---- prologue: tiles 0,1 staged ----
    stage(0, 0);
    stage(1, 1);
    f32x16 sA, sB;

    auto body = [&](int t, f32x16& SCr, f32x16& SNr) {
        // stage(t+2) first (slot (t+2)&3 held t-2, whose readers finished
        // before barrier(t-1)); counted wait drains only tile t+1's 4 loads.
        if (t + 2 < NT) {
            stage(t + 2, (t + 2) & 3);
            asm volatile("s_waitcnt vmcnt(4)" ::: "memory");
        } else {
            asm volatile("s_waitcnt vmcnt(0)" ::: "memory");
        }
        __builtin_amdgcn_s_barrier();
        asm volatile("" ::: "memory");

        // first body: compute S(0) after tile 0 is visible
        if (t == 0) qk_into(SCr, 0, 0.f);

        // QK(t+1) on matrix pipe while softmax(t) runs on VALU below
        if (t + 1 < NT)
            qk_into(SNr, (t + 1) & 3, (t + 1 >= TGT) ? biasl : 0.f);

        // V[t] fragments: 8 lane-linear ds_read_b128 (compiler-scheduled)
        const char* vB = vLane + (unsigned)(t & 3) * 8192u;
        bf8 vf[8];
#pragma unroll
        for (int s = 0; s < 8; ++s)
            vf[s] = *(const bf8*)(vB + s * 1024);

        // static softmax of SC (tile t): exp2 in place, per-lane sum
        float rs = 0.f;
#pragma unroll
        for (int e = 0; e < 16; ++e) {
            SCr[e] = __builtin_amdgcn_exp2f(SCr[e]);
            rs += SCr[e];
        }
        l_run += rs;

        // pack P -> B-operand fragments (cvt_pk + permlane)
        unsigned a0 = cvtpk(SCr[0], SCr[1]),  c0 = cvtpk(SCr[4], SCr[5]);
        unsigned a1 = cvtpk(SCr[2], SCr[3]),  c1 = cvtpk(SCr[6], SCr[7]);
        swap32(a0, c0); swap32(a1, c1);
        const bf8 pf0 = mk_bf8w(a0, a1, c0, c1);
        unsigned a2 = cvtpk(SCr[8], SCr[9]),   c2 = cvtpk(SCr[12], SCr[13]);
        unsigned a3 = cvtpk(SCr[10], SCr[11]), c3 = cvtpk(SCr[14], SCr[15]);
        swap32(a2, c2); swap32(a3, c3);
        const bf8 pf1 = mk_bf8w(a2, a3, c2, c3);

        // PV: two 4-MFMA clusters (A = V^T fragments, lane-linear loaded)
        __builtin_amdgcn_s_setprio(1);
#pragma unroll
        for (int dt = 0; dt < 4; ++dt)
            oa[dt] = __builtin_amdgcn_mfma_f32_32x32x16_bf16(vf[dt], pf0, oa[dt], 0, 0, 0);
#pragma unroll
        for (int dt = 0; dt < 4; ++dt)
            oa[dt] = __builtin_amdgcn_mfma_f32_32x32x16_bf16(vf[4 + dt], pf1, oa[dt], 0, 0, 0);
        __builtin_amdgcn_s_setprio(0);
    };

    for (int t = 0; t < NT; t += 2) {
        body(t, sA, sB);
        body(t + 1, sB, sA);
    }

    // ---- epilogue: single cross-half l merge, normalize, store ----
    const float l_tot = l_run + __shfl_xor(l_run, 32);
    const float inv = 1.0f / l_tot;
    float* op = OUT + ((size_t)(bb * ST + qrow)) * (NH * DH) + hh * DH;
#pragma unroll
    for (int dt = 0; dt < 4; ++dt)
#pragma unroll
        for (int rr = 0; rr < 4; ++rr) {
            f32x4 st;
            st[0] = oa[dt][rr * 4 + 0] * inv;
            st[1] = oa[dt][rr * 4 + 1] * inv;
            st[2] = oa[dt][rr * 4 + 2] * inv;
            st[3] = oa[dt][rr * 4 + 3] * inv;
            *(f32x4*)(op + dt * 32 + rr * 8 + hi * 4) = st;
        }
}

// ---------------- fallback: R16 self-staging kernel (ws too small) ----------
__global__ __launch_bounds__(256, 2)
void attn_fwd_reg(const float* __restrict__ Q,
                  const float* __restrict__ TK,
                  const float* __restrict__ TV,
                  const float* __restrict__ CK,
                  const float* __restrict__ CV,
                  const float* __restrict__ BP,
                  float* __restrict__ OUT)
{
    __shared__ __align__(16) unsigned short Ks[2][KVB * DH];
    __shared__ __align__(16) unsigned short Vs[2][KVB * DH];

    const int tid = threadIdx.x;
    const int w   = tid >> 6;
    const int l   = tid & 63;
    const int r31 = l & 31;
    const int hi  = l >> 5;

    const int bid = blockIdx.x;
    const int xcd = bid & 7;
    const int sub = bid >> 3;
    const int bh  = xcd * 4 + (sub >> 4);
    const int qt  = sub & 15;
    const int bb  = bh >> 4;
    const int hh  = bh & 15;

    const float biasl = BP[0] * LOG2E;

    const int qrow = qt * 128 + w * 32 + r31;
    const float* qp = Q + (((size_t)bb * ST + qrow) * NH + hh) * DH;
    const float qsc = SCALE * LOG2E;
    bf8 qf[8];
#pragma unroll
    for (int dk = 0; dk < 8; ++dk) {
        const f32x4 x0 = *(const f32x4*)(qp + dk * 16 + hi * 8);
        const f32x4 x1 = *(const f32x4*)(qp + dk * 16 + hi * 8 + 4);
        qf[dk] = mk_bf8w(cvtpk(x0[0]*qsc, x0[1]*qsc), cvtpk(x0[2]*qsc, x0[3]*qsc),
                         cvtpk(x1[0]*qsc, x1[1]*qsc), cvtpk(x1[2]*qsc, x1[3]*qsc));
    }

    f32x16 oa[4];
#pragma unroll
    for (int dt = 0; dt < 4; ++dt)
#pragma unroll
        for (int e = 0; e < 16; ++e) oa[dt][e] = 0.f;
    float l_run = 0.f;

    f32x4 skr[2][2], svr[2][2];

    auto stage_load = [&](int t) {
        const int kv0 = t * KVB;
        const float *kb, *vb;
        if (kv0 < ST) {
            const size_t off = (((size_t)bb * ST + kv0) * NH + hh) * DH;
            kb = TK + off; vb = TV + off;
        } else {
            const size_t off = (((size_t)bb * SC + (kv0 - ST)) * NH + hh) * DH;
            kb = CK + off; vb = CV + off;
        }
#pragma unroll
        for (int i = 0; i < 2; ++i) {
            const int c = tid + (i << 8);
            const int krow = c >> 4;
            const int kcol = ((c & 15) ^ (krow & 7)) << 3;
            const float* kp = kb + (size_t)krow * (NH * DH) + kcol;
            skr[i][0] = *(const f32x4*)kp;
            skr[i][1] = *(const f32x4*)(kp + 4);
            const int vkv = (((c >> 8) & 1) << 4) | (((c >> 4) & 1) << 3)
                          | (((c >> 7) & 1) << 2) | ((c >> 1) & 3);
            const int vd  = (((c >> 5) & 3) << 5) | (((c >> 3) & 1) << 4)
                          | ((c & 1) << 3);
            const float* vp = vb + (size_t)vkv * (NH * DH) + vd;
            svr[i][0] = *(const f32x4*)vp;
            svr[i][1] = *(const f32x4*)(vp + 4);
        }
    };
    auto stage_write = [&](int buf) {
#pragma unroll
        for (int i = 0; i < 2; ++i) {
            const int c = tid + (i << 8);
            *(bf8*)((char*)Ks[buf] + c * 16) = pack_bf8(skr[i][0], skr[i][1]);
            *(bf8*)((char*)Vs[buf] + c * 16) = pack_bf8(svr[i][0], svr[i][1]);
        }
    };

    stage_load(0);
    stage_write(0);

    const unsigned vLane = (unsigned)(size_t)&Vs[0][0]
                         + (unsigned)((l >> 4) * 128 + (l & 15) * 8);

    for (int t = 0; t < NT; ++t) {
        __syncthreads();
        if (t + 1 < NT) stage_load(t + 1);
        const int buf = t & 1;
        const float bias = (t >= TGT) ? biasl : 0.f;

        f32x16 s0;
#pragma unroll
        for (int e = 0; e < 16; ++e) s0[e] = bias;
        __builtin_amdgcn_s_setprio(1);
#pragma unroll
        for (int dk = 0; dk < 8; ++dk) {
            int o = r31 * 256 + (dk * 16 + hi * 8) * 2;
            o ^= (r31 & 7) << 4;
            const bf8 kf = *(const bf8*)((const char*)Ks[buf] + o);
            s0 = __builtin_amdgcn_mfma_f32_32x32x16_bf16(kf, qf[dk], s0, 0, 0, 0);
        }
        __builtin_amdgcn_s_setprio(0);

        asm volatile("" ::: "memory");
        const unsigned vA = vLane + (unsigned)(buf << 13);
        i32x2 vt_[2][4][2];
#pragma unroll
        for (int ks = 0; ks < 2; ++ks) {
            const unsigned vk = vA + (unsigned)(ks << 12);
#pragma unroll
            for (int dt = 0; dt < 4; ++dt) {
                vt_[ks][dt][0] = tr_read(vk + dt * 512);
                vt_[ks][dt][1] = tr_read(vk + dt * 512 + 2048);
            }
        }

        if (t + 1 < NT) stage_write(buf ^ 1);

        float rs = 0.f;
#pragma unroll
        for (int e = 0; e < 16; ++e) {
            s0[e] = __builtin_amdgcn_exp2f(s0[e]);
            rs += s0[e];
        }
        l_run += rs;

        unsigned a0 = cvtpk(s0[0], s0[1]),  b0 = cvtpk(s0[4], s0[5]);
        unsigned a1 = cvtpk(s0[2], s0[3]),  b1 = cvtpk(s0[6], s0[7]);
        swap32(a0, b0); swap32(a1, b1);
        const bf8 pf0 = mk_bf8w(a0, a1, b0, b1);
        unsigned a2 = cvtpk(s0[8], s0[9]),   b2 = cvtpk(s0[12], s0[13]);
        unsigned a3 = cvtpk(s0[10], s0[11]), b3 = cvtpk(s0[14], s0[15]);
        swap32(a2, b2); swap32(a3, b3);
        const bf8 pf1 = mk_bf8w(a2, a3, b2, b3);

        asm volatile("s_waitcnt lgkmcnt(0)");
        __builtin_amdgcn_sched_barrier(0);
        __builtin_amdgcn_s_setprio(1);
#pragma unroll
        for (int ks = 0; ks < 2; ++ks) {
            const bf8 pf = ks ? pf1 : pf0;
#pragma unroll
            for (int dt = 0; dt < 4; ++dt) {
                const bf8 vf = mk_bf8(vt_[ks][dt][0], vt_[ks][dt][1]);
                oa[dt] = __builtin_amdgcn_mfma_f32_32x32x16_bf16(vf, pf, oa[dt], 0, 0, 0);
            }
        }
        __builtin_amdgcn_s_setprio(0);
    }

    const float l_tot = l_run + __shfl_xor(l_run, 32);
    const float inv = 1.0f / l_tot;
    float* op = OUT + ((size_t)(bb * ST + qrow)) * (NH * DH) + hh * DH;
#pragma unroll
    for (int dt = 0; dt < 4; ++dt)
#pragma unroll
        for (int rr = 0; rr < 4; ++rr) {
            f32x4 st;
            st[0] = oa[dt][rr * 4 + 0] * inv;
            st[1] = oa[dt][rr * 4 + 1] * inv;
            st[2] = oa[dt][rr * 4 + 2] * inv;
            st[3] = oa[dt][rr * 4 + 3] * inv;
            *(f32x4*)(op + dt * 32 + rr * 8 + hi * 4) = st;
        }
}

extern "C" void kernel_launch(void* const* d_in, const int* in_sizes, int n_in,
                              void* d_out, int out_size, void* d_ws, size_t ws_size,
                              hipStream_t stream) {
    const float* q  = (const float*)d_in[0];
    const float* tk = (const float*)d_in[1];
    const float* tv = (const float*)d_in[2];
    const float* ck = (const float*)d_in[3];
    const float* cv = (const float*)d_in[4];
    const float* bp = (const float*)d_in[5];
    float* out = (float*)d_out;

    if (ws_size >= WS_NEED) {
        unsigned* kp = (unsigned*)d_ws;
        unsigned* vp = (unsigned*)((char*)d_ws + PRE_BYTES);
        preconv<<<dim3(6144), 256, 0, stream>>>(tk, tv, ck, cv, kp, vp);
        attn_fwd_pre<<<dim3(512), 256, 0, stream>>>(q, kp, vp, bp, out);
    } else {
        attn_fwd_reg<<<dim3(512), 256, 0, stream>>>(q, tk, tv, ck, cv, bp, out);
    }
}

// Round 24
// 138.813 us; speedup vs baseline: 1.1807x; 1.0229x over previous
//
#include <hip/hip_runtime.h>
#include <hip/hip_bf16.h>

typedef __attribute__((ext_vector_type(4))) float f32x4;
typedef __attribute__((ext_vector_type(16))) float f32x16;
typedef __attribute__((ext_vector_type(8))) short bf8;
typedef __attribute__((ext_vector_type(2))) int i32x2;

#define B_ 2
#define ST 2048
#define SC 1024
#define SK 3072
#define NH 16
#define DH 128
#define KVB 32
#define NT 96
#define TGT 64
#define SCALE 0.088388347648318447f
#define LOG2E 1.4426950408889634f
// pre-converted KV workspace: 32 bh x 96 tiles x 512 chunks x 16 B, K then V
// chunk = exact 16B MFMA fragment for lane l (lane-linear LDS, conflict-free)
#define PRE_TILE_U32 2048
#define PRE_BYTES (32ull * 96 * 512 * 16)
#define WS_NEED (2ull * PRE_BYTES)

__device__ __forceinline__ i32x2 tr_read(unsigned a) {
    i32x2 d;
    asm volatile("ds_read_b64_tr_b16 %0, %1" : "=v"(d) : "v"(a));
    return d;
}

__device__ __forceinline__ unsigned cvtpk(float lo, float hi) {
    unsigned r;
    asm("v_cvt_pk_bf16_f32 %0, %1, %2" : "=v"(r) : "v"(lo), "v"(hi));
    return r;
}

// v_permlane32_swap_b32: SAFE only with two independently-computed values
// (P-pack, proven R7). BROKEN as copy-then-swap self-reduce (R6/R8).
__device__ __forceinline__ void swap32(unsigned &a, unsigned &b) {
    asm volatile("v_permlane32_swap_b32 %0, %1" : "+v"(a), "+v"(b));
}

__device__ __forceinline__ bf8 mk_bf8(i32x2 a, i32x2 b) {
    union { i32x2 h[2]; bf8 v; } u;
    u.h[0] = a; u.h[1] = b;
    return u.v;
}
__device__ __forceinline__ bf8 mk_bf8w(unsigned w0, unsigned w1, unsigned w2, unsigned w3) {
    union { unsigned w[4]; bf8 v; } u;
    u.w[0] = w0; u.w[1] = w1; u.w[2] = w2; u.w[3] = w3;
    return u.v;
}
__device__ __forceinline__ bf8 pack_bf8(f32x4 a, f32x4 b) {
    return mk_bf8w(cvtpk(a[0], a[1]), cvtpk(a[2], a[3]),
                   cvtpk(b[0], b[1]), cvtpk(b[2], b[3]));
}

// ---------------- pre-pass: fp32 KV -> bf16 fragments in lane-linear order ----
__global__ __launch_bounds__(256)
void preconv(const float* __restrict__ TK, const float* __restrict__ TV,
             const float* __restrict__ CK, const float* __restrict__ CV,
             unsigned* __restrict__ KP, unsigned* __restrict__ VP)
{
    const unsigned gid = blockIdx.x * 256 + threadIdx.x;   // 0..1572863
    const int c    = gid & 511;
    const int idx  = gid >> 9;          // bh*96 + t
    const int bhid = idx / 96;
    const int t    = idx - bhid * 96;
    const int bb   = bhid >> 4;
    const int hh   = bhid & 15;
    const int lc   = c & 63;
    const int r31c = lc & 31;
    const int hic  = lc >> 5;

    const bool tgt = (t < TGT);
    const size_t krowbase = tgt
        ? (((size_t)bb * ST + t * 32) * NH + hh) * DH
        : (((size_t)bb * SC + (t * 32 - ST)) * NH + hh) * DH;
    const float* kb = (tgt ? TK : CK) + krowbase;
    const float* vb = (tgt ? TV : CV) + krowbase;

    // K chunk: dk = c>>6; lane fragment = K[kv=r31][dk*16 + hi*8 + j], j=0..7
    {
        const int dk = c >> 6;
        const float* kp = kb + (size_t)r31c * (NH * DH) + dk * 16 + hic * 8;
        const f32x4 k0 = *(const f32x4*)kp;
        const f32x4 k1 = *(const f32x4*)(kp + 4);
        unsigned* ko = KP + (size_t)gid * 4;
        ko[0] = cvtpk(k0[0], k0[1]); ko[1] = cvtpk(k0[2], k0[3]);
        ko[2] = cvtpk(k1[0], k1[1]); ko[3] = cvtpk(k1[2], k1[3]);
    }

    // V chunk: s = c>>6 = ks*4+dt; lane fragment = V^T[d=dt*32+(lc&31)]
    //          [kv = ks*16 + hi*8 + j] = V[kv+j][d]
    {
        const int s  = c >> 6;
        const int ks = s >> 2;
        const int dt = s & 3;
        const int d  = dt * 32 + r31c;
        const float* vp = vb + (size_t)(ks * 16 + hic * 8) * (NH * DH) + d;
        float vv[8];
#pragma unroll
        for (int j = 0; j < 8; ++j) vv[j] = vp[(size_t)j * (NH * DH)];
        unsigned* vo = VP + (size_t)gid * 4;
        vo[0] = cvtpk(vv[0], vv[1]); vo[1] = cvtpk(vv[2], vv[3]);
        vo[2] = cvtpk(vv[4], vv[5]); vo[3] = cvtpk(vv[6], vv[7]);
    }
}

// ---------------- main: lane-linear LDS + counted vmcnt + T15 pipeline -------
__global__ __launch_bounds__(256) __attribute__((amdgpu_waves_per_eu(2, 2)))
void attn_fwd_pre(const float* __restrict__ Q,
                  const unsigned* __restrict__ KP,
                  const unsigned* __restrict__ VP,
                  const float* __restrict__ BP,
                  float* __restrict__ OUT)
{
    // All LDS reads are ds_read_b128 at base + l*16 + imm offset: conflict-free.
    __shared__ __align__(16) unsigned short Ks[3][KVB * DH];   // 3 x 8 KB
    __shared__ __align__(16) unsigned short Vs[3][KVB * DH];   // 3 x 8 KB

    const int tid = threadIdx.x;
    const int w   = tid >> 6;
    const int l   = tid & 63;
    const int r31 = l & 31;
    const int hi  = l >> 5;

    // XCD-aware mapping: 512 blocks = 8 XCD x 4 bh x 16 q-tiles
    const int bid = blockIdx.x;
    const int xcd = bid & 7;
    const int sub = bid >> 3;
    const int bh  = xcd * 4 + (sub >> 4);
    const int qt  = sub & 15;
    const int bb  = bh >> 4;
    const int hh  = bh & 15;
    const int bh96 = bh * 96;

    const float biasl = BP[0] * LOG2E;

    // ---- Q fragments (B-operand), pre-scaled by SCALE*log2(e) ----
    const int qrow = qt * 128 + w * 32 + r31;
    const float* qp = Q + (((size_t)bb * ST + qrow) * NH + hh) * DH;
    const float qsc = SCALE * LOG2E;
    bf8 qf[8];
#pragma unroll
    for (int dk = 0; dk < 8; ++dk) {
        const f32x4 x0 = *(const f32x4*)(qp + dk * 16 + hi * 8);
        const f32x4 x1 = *(const f32x4*)(qp + dk * 16 + hi * 8 + 4);
        qf[dk] = mk_bf8w(cvtpk(x0[0]*qsc, x0[1]*qsc), cvtpk(x0[2]*qsc, x0[3]*qsc),
                         cvtpk(x1[0]*qsc, x1[1]*qsc), cvtpk(x1[2]*qsc, x1[3]*qsc));
    }

    f32x16 oa[4];
#pragma unroll
    for (int dt = 0; dt < 4; ++dt)
#pragma unroll
        for (int e = 0; e < 16; ++e) oa[dt][e] = 0.f;
    float l_run = 0.f;

    auto stage = [&](int t, int buf) {
        const unsigned* kt = KP + (size_t)(bh96 + t) * PRE_TILE_U32;
        const unsigned* vt = VP + (size_t)(bh96 + t) * PRE_TILE_U32;
#pragma unroll
        for (int i = 0; i < 2; ++i) {
            const int cb = (w << 6) + (i << 8);
            const unsigned kdst = (unsigned)(size_t)&Ks[buf][cb * 8];
            const unsigned vdst = (unsigned)(size_t)&Vs[buf][cb * 8];
            const unsigned* kg = kt + (size_t)(cb + l) * 4;
            const unsigned* vg = vt + (size_t)(cb + l) * 4;
            __builtin_amdgcn_global_load_lds(
                (const __attribute__((address_space(1))) unsigned*)(size_t)kg,
                (__attribute__((address_space(3))) unsigned*)(size_t)kdst, 16, 0, 0);
            __builtin_amdgcn_global_load_lds(
                (const __attribute__((address_space(1))) unsigned*)(size_t)vg,
                (__attribute__((address_space(3))) unsigned*)(size_t)vdst, 16, 0, 0);
        }
    };

    const char* kLane = (const char*)&Ks[0][0] + l * 16;
    const char* vLane = (const char*)&Vs[0][0] + l * 16;

    auto qk_into = [&](f32x16& SN, int bufn, float biasn) {
#pragma unroll
        for (int e = 0; e < 16; ++e) SN[e] = biasn;
        const char* kB = kLane + (unsigned)bufn * 8192u;
        __builtin_amdgcn_s_setprio(1);
#pragma unroll
        for (int dk = 0; dk < 8; ++dk) {
            const bf8 kf = *(const bf8*)(kB + dk * 1024);
            SN = __builtin_amdgcn_mfma_f32_32x32x16_bf16(kf, qf[dk], SN, 0, 0, 0);
        }
        __builtin_amdgcn_s_setprio(0);
    };

    // ---- prologue: tiles 0,1 staged; tile0 visible; S(0) computed ----
    stage(0, 0);
    stage(1, 1);
    asm volatile("s_waitcnt vmcnt(4)" ::: "memory");
    __builtin_amdgcn_s_barrier();
    asm volatile("" ::: "memory");
    f32x16 sA, sB;
    qk_into(sA, 0, 0.f);

    int b0 = 0, b1 = 1, b2 = 2;

    auto body = [&](int t, f32x16& SCr, f32x16& SNr) {
        if (t + 1 < NT) asm volatile("s_waitcnt vmcnt(0)" ::: "memory");
        __builtin_amdgcn_s_barrier();
        asm volatile("" ::: "memory");
        if (t + 2 < NT) stage(t + 2, b2);

        // QK(t+1) on matrix pipe while softmax(t) runs on VALU below
        if (t + 1 < NT)
            qk_into(SNr, b1, (t + 1 >= TGT) ? biasl : 0.f);

        // V[t] fragments: 8 lane-linear ds_read_b128 (compiler-scheduled)
        const char* vB = vLane + (unsigned)b0 * 8192u;
        bf8 vf[8];
#pragma unroll
        for (int s = 0; s < 8; ++s)
            vf[s] = *(const bf8*)(vB + s * 1024);

        // static softmax of SC (tile t): exp2 in place, per-lane sum
        float rs = 0.f;
#pragma unroll
        for (int e = 0; e < 16; ++e) {
            SCr[e] = __builtin_amdgcn_exp2f(SCr[e]);
            rs += SCr[e];
        }
        l_run += rs;

        // pack P -> B-operand fragments (cvt_pk + permlane)
        unsigned a0 = cvtpk(SCr[0], SCr[1]),  c0 = cvtpk(SCr[4], SCr[5]);
        unsigned a1 = cvtpk(SCr[2], SCr[3]),  c1 = cvtpk(SCr[6], SCr[7]);
        swap32(a0, c0); swap32(a1, c1);
        const bf8 pf0 = mk_bf8w(a0, a1, c0, c1);
        unsigned a2 = cvtpk(SCr[8], SCr[9]),   c2 = cvtpk(SCr[12], SCr[13]);
        unsigned a3 = cvtpk(SCr[10], SCr[11]), c3 = cvtpk(SCr[14], SCr[15]);
        swap32(a2, c2); swap32(a3, c3);
        const bf8 pf1 = mk_bf8w(a2, a3, c2, c3);

        // PV: two 4-MFMA clusters (A = V^T fragments, lane-linear loaded)
        __builtin_amdgcn_s_setprio(1);
#pragma unroll
        for (int dt = 0; dt < 4; ++dt)
            oa[dt] = __builtin_amdgcn_mfma_f32_32x32x16_bf16(vf[dt], pf0, oa[dt], 0, 0, 0);
#pragma unroll
        for (int dt = 0; dt < 4; ++dt)
            oa[dt] = __builtin_amdgcn_mfma_f32_32x32x16_bf16(vf[4 + dt], pf1, oa[dt], 0, 0, 0);
        __builtin_amdgcn_s_setprio(0);

        // rotate buffers
        const int n0 = b1, n1 = b2, n2 = b0;
        b0 = n0; b1 = n1; b2 = n2;
    };

    for (int t = 0; t < NT; t += 2) {
        body(t, sA, sB);
        body(t + 1, sB, sA);
    }

    // ---- epilogue: single cross-half l merge, normalize, store ----
    const float l_tot = l_run + __shfl_xor(l_run, 32);
    const float inv = 1.0f / l_tot;
    float* op = OUT + ((size_t)(bb * ST + qrow)) * (NH * DH) + hh * DH;
#pragma unroll
    for (int dt = 0; dt < 4; ++dt)
#pragma unroll
        for (int rr = 0; rr < 4; ++rr) {
            f32x4 st;
            st[0] = oa[dt][rr * 4 + 0] * inv;
            st[1] = oa[dt][rr * 4 + 1] * inv;
            st[2] = oa[dt][rr * 4 + 2] * inv;
            st[3] = oa[dt][rr * 4 + 3] * inv;
            *(f32x4*)(op + dt * 32 + rr * 8 + hi * 4) = st;
        }
}

// ---------------- fallback: R16 self-staging kernel (ws too small) ----------
__global__ __launch_bounds__(256, 2)
void attn_fwd_reg(const float* __restrict__ Q,
                  const float* __restrict__ TK,
                  const float* __restrict__ TV,
                  const float* __restrict__ CK,
                  const float* __restrict__ CV,
                  const float* __restrict__ BP,
                  float* __restrict__ OUT)
{
    __shared__ __align__(16) unsigned short Ks[2][KVB * DH];
    __shared__ __align__(16) unsigned short Vs[2][KVB * DH];

    const int tid = threadIdx.x;
    const int w   = tid >> 6;
    const int l   = tid & 63;
    const int r31 = l & 31;
    const int hi  = l >> 5;

    const int bid = blockIdx.x;
    const int xcd = bid & 7;
    const int sub = bid >> 3;
    const int bh  = xcd * 4 + (sub >> 4);
    const int qt  = sub & 15;
    const int bb  = bh >> 4;
    const int hh  = bh & 15;

    const float biasl = BP[0] * LOG2E;

    const int qrow = qt * 128 + w * 32 + r31;
    const float* qp = Q + (((size_t)bb * ST + qrow) * NH + hh) * DH;
    const float qsc = SCALE * LOG2E;
    bf8 qf[8];
#pragma unroll
    for (int dk = 0; dk < 8; ++dk) {
        const f32x4 x0 = *(const f32x4*)(qp + dk * 16 + hi * 8);
        const f32x4 x1 = *(const f32x4*)(qp + dk * 16 + hi * 8 + 4);
        qf[dk] = mk_bf8w(cvtpk(x0[0]*qsc, x0[1]*qsc), cvtpk(x0[2]*qsc, x0[3]*qsc),
                         cvtpk(x1[0]*qsc, x1[1]*qsc), cvtpk(x1[2]*qsc, x1[3]*qsc));
    }

    f32x16 oa[4];
#pragma unroll
    for (int dt = 0; dt < 4; ++dt)
#pragma unroll
        for (int e = 0; e < 16; ++e) oa[dt][e] = 0.f;
    float l_run = 0.f;

    f32x4 skr[2][2], svr[2][2];

    auto stage_load = [&](int t) {
        const int kv0 = t * KVB;
        const float *kb, *vb;
        if (kv0 < ST) {
            const size_t off = (((size_t)bb * ST + kv0) * NH + hh) * DH;
            kb = TK + off; vb = TV + off;
        } else {
            const size_t off = (((size_t)bb * SC + (kv0 - ST)) * NH + hh) * DH;
            kb = CK + off; vb = CV + off;
        }
#pragma unroll
        for (int i = 0; i < 2; ++i) {
            const int c = tid + (i << 8);
            const int krow = c >> 4;
            const int kcol = ((c & 15) ^ (krow & 7)) << 3;
            const float* kp = kb + (size_t)krow * (NH * DH) + kcol;
            skr[i][0] = *(const f32x4*)kp;
            skr[i][1] = *(const f32x4*)(kp + 4);
            const int vkv = (((c >> 8) & 1) << 4) | (((c >> 4) & 1) << 3)
                          | (((c >> 7) & 1) << 2) | ((c >> 1) & 3);
            const int vd  = (((c >> 5) & 3) << 5) | (((c >> 3) & 1) << 4)
                          | ((c & 1) << 3);
            const float* vp = vb + (size_t)vkv * (NH * DH) + vd;
            svr[i][0] = *(const f32x4*)vp;
            svr[i][1] = *(const f32x4*)(vp + 4);
        }
    };
    auto stage_write = [&](int buf) {
#pragma unroll
        for (int i = 0; i < 2; ++i) {
            const int c = tid + (i << 8);
            *(bf8*)((char*)Ks[buf] + c * 16) = pack_bf8(skr[i][0], skr[i][1]);
            *(bf8*)((char*)Vs[buf] + c * 16) = pack_bf8(svr[i][0], svr[i][1]);
        }
    };

    stage_load(0);
    stage_write(0);

    const unsigned vLane = (unsigned)(size_t)&Vs[0][0]
                         + (unsigned)((l >> 4) * 128 + (l & 15) * 8);

    for (int t = 0; t < NT; ++t) {
        __syncthreads();
        if (t + 1 < NT) stage_load(t + 1);
        const int buf = t & 1;
        const float bias = (t >= TGT) ? biasl : 0.f;

        f32x16 s0;
#pragma unroll
        for (int e = 0; e < 16; ++e) s0[e] = bias;
        __builtin_amdgcn_s_setprio(1);
#pragma unroll
        for (int dk = 0; dk < 8; ++dk) {
            int o = r31 * 256 + (dk * 16 + hi * 8) * 2;
            o ^= (r31 & 7) << 4;
            const bf8 kf = *(const bf8*)((const char*)Ks[buf] + o);
            s0 = __builtin_amdgcn_mfma_f32_32x32x16_bf16(kf, qf[dk], s0, 0, 0, 0);
        }
        __builtin_amdgcn_s_setprio(0);

        asm volatile("" ::: "memory");
        const unsigned vA = vLane + (unsigned)(buf << 13);
        i32x2 vt_[2][4][2];
#pragma unroll
        for (int ks = 0; ks < 2; ++ks) {
            const unsigned vk = vA + (unsigned)(ks << 12);
#pragma unroll
            for (int dt = 0; dt < 4; ++dt) {
                vt_[ks][dt][0] = tr_read(vk + dt * 512);
                vt_[ks][dt][1] = tr_read(vk + dt * 512 + 2048);
            }
        }

        if (t + 1 < NT) stage_write(buf ^ 1);

        float rs = 0.f;
#pragma unroll
        for (int e = 0; e < 16; ++e) {
            s0[e] = __builtin_amdgcn_exp2f(s0[e]);
            rs += s0[e];
        }
        l_run += rs;

        unsigned a0 = cvtpk(s0[0], s0[1]),  b0 = cvtpk(s0[4], s0[5]);
        unsigned a1 = cvtpk(s0[2], s0[3]),  b1 = cvtpk(s0[6], s0[7]);
        swap32(a0, b0); swap32(a1, b1);
        const bf8 pf0 = mk_bf8w(a0, a1, b0, b1);
        unsigned a2 = cvtpk(s0[8], s0[9]),   b2 = cvtpk(s0[12], s0[13]);
        unsigned a3 = cvtpk(s0[10], s0[11]), b3 = cvtpk(s0[14], s0[15]);
        swap32(a2, b2); swap32(a3, b3);
        const bf8 pf1 = mk_bf8w(a2, a3, b2, b3);

        asm volatile("s_waitcnt lgkmcnt(0)");
        __builtin_amdgcn_sched_barrier(0);
        __builtin_amdgcn_s_setprio(1);
#pragma unroll
        for (int ks = 0; ks < 2; ++ks) {
            const bf8 pf = ks ? pf1 : pf0;
#pragma unroll
            for (int dt = 0; dt < 4; ++dt) {
                const bf8 vf = mk_bf8(vt_[ks][dt][0], vt_[ks][dt][1]);
                oa[dt] = __builtin_amdgcn_mfma_f32_32x32x16_bf16(vf, pf, oa[dt], 0, 0, 0);
            }
        }
        __builtin_amdgcn_s_setprio(0);
    }

    const float l_tot = l_run + __shfl_xor(l_run, 32);
    const float inv = 1.0f / l_tot;
    float* op = OUT + ((size_t)(bb * ST + qrow)) * (NH * DH) + hh * DH;
#pragma unroll
    for (int dt = 0; dt < 4; ++dt)
#pragma unroll
        for (int rr = 0; rr < 4; ++rr) {
            f32x4 st;
            st[0] = oa[dt][rr * 4 + 0] * inv;
            st[1] = oa[dt][rr * 4 + 1] * inv;
            st[2] = oa[dt][rr * 4 + 2] * inv;
            st[3] = oa[dt][rr * 4 + 3] * inv;
            *(f32x4*)(op + dt * 32 + rr * 8 + hi * 4) = st;
        }
}

extern "C" void kernel_launch(void* const* d_in, const int* in_sizes, int n_in,
                              void* d_out, int out_size, void* d_ws, size_t ws_size,
                              hipStream_t stream) {
    const float* q  = (const float*)d_in[0];
    const float* tk = (const float*)d_in[1];
    const float* tv = (const float*)d_in[2];
    const float* ck = (const float*)d_in[3];
    const float* cv = (const float*)d_in[4];
    const float* bp = (const float*)d_in[5];
    float* out = (float*)d_out;

    if (ws_size >= WS_NEED) {
        unsigned* kp = (unsigned*)d_ws;
        unsigned* vp = (unsigned*)((char*)d_ws + PRE_BYTES);
        preconv<<<dim3(6144), 256, 0, stream>>>(tk, tv, ck, cv, kp, vp);
        attn_fwd_pre<<<dim3(512), 256, 0, stream>>>(q, kp, vp, bp, out);
    } else {
        attn_fwd_reg<<<dim3(512), 256, 0, stream>>>(q, tk, tv, ck, cv, bp, out);
    }
}